// Round 10
// baseline (226.536 us; speedup 1.0000x reference)
//
#include <hip/hip_runtime.h>
#include <hip/hip_bf16.h>
#include <stdint.h>

constexpr int FN   = 64;
constexpr int HIDN = 32;
constexpr int FMSG = 64;
constexpr int FOUT = 128;

using short8 = __attribute__((ext_vector_type(8))) short;
using f32x4  = __attribute__((ext_vector_type(4))) float;

union Frag { short8 v; uint32_t u[4]; };

__device__ __forceinline__ uint32_t packrn(float a, float b) {
    union { __hip_bfloat162 h; uint32_t u; } cv;
    cv.h = __float22bfloat162_rn(make_float2(a, b));   // v_cvt_pk_bf16_f32
    return cv.u;
}
__device__ __forceinline__ float bf16_to_f(uint32_t h16) {
    return __uint_as_float(h16 << 16);
}

__device__ __forceinline__ int node_of(const int* __restrict__ offs, int N, int target) {
    int l = 0, r = N + 1;
    while (l + 1 < r) {
        const int m = (l + r) >> 1;
        if (offs[m] <= target) l = m; else r = m;
    }
    return l;
}

// ---------------------------------------------------------------------------
// zero_cnt: replaces hipMemsetAsync (which costs a flat ~118 us in-graph).
// ---------------------------------------------------------------------------
__global__ __launch_bounds__(256) void zero_cnt_kernel(int* __restrict__ cnt, int N)
{
    const int i = blockIdx.x * 256 + threadIdx.x;
    if (i < N) cnt[i] = 0;
}

// ---------------------------------------------------------------------------
// hist: 800k device-scope atomicAdd-with-return (rank = arrival order).
// ---------------------------------------------------------------------------
__global__ __launch_bounds__(256) void hist_kernel(
    const int* __restrict__ ei, int* __restrict__ cnt, int* __restrict__ rank,
    int E)
{
    const int e4 = (blockIdx.x * 256 + threadIdx.x) * 4;
    if (e4 + 3 < E) {
        const int4 c = *reinterpret_cast<const int4*>(ei + E + e4);
        int4 r;
        r.x = atomicAdd(cnt + c.x, 1);
        r.y = atomicAdd(cnt + c.y, 1);
        r.z = atomicAdd(cnt + c.z, 1);
        r.w = atomicAdd(cnt + c.w, 1);
        *reinterpret_cast<int4*>(rank + e4) = r;
    } else {
        for (int e = e4; e < E; ++e) rank[e] = atomicAdd(cnt + ei[E + e], 1);
    }
}

// ---------------------------------------------------------------------------
// prep_rest: [0,BP) node_pre | [BP] pack + Qu | [BP+1, BP+1+BZ) agg zero
// ---------------------------------------------------------------------------
__global__ __launch_bounds__(256) void prep_rest_kernel(
    const float* __restrict__ x, const float* __restrict__ u,
    const float* __restrict__ W1, const float* __restrict__ b1,
    const float* __restrict__ W2,
    const float* __restrict__ W3, const float* __restrict__ b3,
    const float* __restrict__ W4,
    float* __restrict__ Pa, float* __restrict__ Pb, float* __restrict__ Qc,
    float* __restrict__ Qu,
    uint32_t* __restrict__ PW1, uint32_t* __restrict__ PW2,
    uint32_t* __restrict__ PW3, uint32_t* __restrict__ PW4,
    uint4* __restrict__ zbase, size_t zquads,
    int N, int G, int BP, int BZ)
{
    const int b   = blockIdx.x;
    const int tid = threadIdx.x;

    if (b < BP) {
        const int n = b * 256 + tid;
        if (n >= N) return;
        float a[HIDN], bq[HIDN], c[HIDN];
#pragma unroll
        for (int j = 0; j < HIDN; ++j) { a[j] = b1[j]; bq[j] = 0.0f; c[j] = b3[j]; }
        const float* xr = x + (size_t)n * FN;
        const float* WA = W1;
        const float* WB = W1 + FN * HIDN;
        const float* WX = W3;                   // rows 0..63 of W3
#pragma unroll 2
        for (int k = 0; k < FN; k += 4) {
            const float4 v = *reinterpret_cast<const float4*>(xr + k);
            const float* wa = WA + k * HIDN;
            const float* wb = WB + k * HIDN;
            const float* wc = WX + k * HIDN;
#pragma unroll
            for (int j = 0; j < HIDN; ++j) {
                float aj = a[j], bj = bq[j], cj = c[j];
                aj = fmaf(v.x, wa[j], aj);            bj = fmaf(v.x, wb[j], bj);            cj = fmaf(v.x, wc[j], cj);
                aj = fmaf(v.y, wa[HIDN + j], aj);     bj = fmaf(v.y, wb[HIDN + j], bj);     cj = fmaf(v.y, wc[HIDN + j], cj);
                aj = fmaf(v.z, wa[2 * HIDN + j], aj); bj = fmaf(v.z, wb[2 * HIDN + j], bj); cj = fmaf(v.z, wc[2 * HIDN + j], cj);
                aj = fmaf(v.w, wa[3 * HIDN + j], aj); bj = fmaf(v.w, wb[3 * HIDN + j], bj); cj = fmaf(v.w, wc[3 * HIDN + j], cj);
                a[j] = aj; bq[j] = bj; c[j] = cj;
            }
        }
        float4* pa = reinterpret_cast<float4*>(Pa + (size_t)n * HIDN);
        float4* pb = reinterpret_cast<float4*>(Pb + (size_t)n * HIDN);
        float4* qc = reinterpret_cast<float4*>(Qc + (size_t)n * HIDN);
#pragma unroll
        for (int q = 0; q < HIDN / 4; ++q) {
            pa[q] = make_float4(a[4*q], a[4*q+1], a[4*q+2], a[4*q+3]);
            pb[q] = make_float4(bq[4*q], bq[4*q+1], bq[4*q+2], bq[4*q+3]);
            qc[q] = make_float4(c[4*q], c[4*q+1], c[4*q+2], c[4*q+3]);
        }
        return;
    }
    if (b == BP) {
        // ---- pack weights + Qu = u@W3d (per graph) ----
        const float* WC = W1 + 2 * FN * HIDN;
        for (int i = tid; i < 1024; i += 256) {          // PW1[j<32][k2<32]
            const int j = i >> 5, k2 = i & 31;
            PW1[i] = packrn(WC[(2 * k2) * HIDN + j], WC[(2 * k2 + 1) * HIDN + j]);
        }
        for (int i = tid; i < 1024; i += 256) {          // PW2[j<64][k2<16]
            const int j = i >> 4, k2 = i & 15;
            PW2[i] = packrn(W2[(2 * k2) * FMSG + j], W2[(2 * k2 + 1) * FMSG + j]);
        }
        const float* W3m = W3 + 64 * HIDN;               // rows 64..191 (mean|max)
        for (int i = tid; i < 2048; i += 256) {          // PW3[j<32][k2<64]
            const int j = i >> 6, k2 = i & 63;
            PW3[i] = packrn(W3m[(2 * k2) * HIDN + j], W3m[(2 * k2 + 1) * HIDN + j]);
        }
        for (int i = tid; i < 2048; i += 256) {          // PW4[j<128][k2<16]
            const int j = i >> 4, k2 = i & 15;
            PW4[i] = packrn(W4[(2 * k2) * FOUT + j], W4[(2 * k2 + 1) * FOUT + j]);
        }
        const float* W3u = W3 + 192 * HIDN;              // rows 192..255 (u part)
        for (int i = tid; i < G * HIDN; i += 256) {      // Qu[g][j]
            const int g = i >> 5, j = i & 31;
            const float* ur = u + (size_t)g * FN;
            float acc = 0.0f;
#pragma unroll 8
            for (int k = 0; k < FN; ++k) acc = fmaf(ur[k], W3u[k * HIDN + j], acc);
            Qu[i] = acc;
        }
        return;
    }
    // ---- zero agg_sum/agg_maxb (grid-stride uint4) ----
    const size_t stride = (size_t)BZ * 256;
    const uint4 z = make_uint4(0u, 0u, 0u, 0u);
    for (size_t i = (size_t)(b - BP - 1) * 256 + tid; i < zquads; i += stride)
        zbase[i] = z;
}

// ---------------------------------------------------------------------------
// Multi-block scan over cnt[N] -> offs[N+1]
// ---------------------------------------------------------------------------
__global__ __launch_bounds__(256) void scanA_kernel(
    const int* __restrict__ cnt, int* __restrict__ part, int N)
{
    __shared__ int red[256];
    const int tid  = threadIdx.x;
    const int base = blockIdx.x * 2048 + tid * 8;
    int s = 0;
    if (base + 8 <= N) {
        const int4 a = *reinterpret_cast<const int4*>(cnt + base);
        const int4 b = *reinterpret_cast<const int4*>(cnt + base + 4);
        s = a.x + a.y + a.z + a.w + b.x + b.y + b.z + b.w;
    } else {
        for (int i = base; i < min(base + 8, N); ++i) s += cnt[i];
    }
    red[tid] = s;
    __syncthreads();
    for (int d = 128; d > 0; d >>= 1) {
        if (tid < d) red[tid] += red[tid + d];
        __syncthreads();
    }
    if (tid == 0) part[blockIdx.x] = red[0];
}

__global__ __launch_bounds__(64) void scanB_kernel(
    const int* __restrict__ part, int* __restrict__ partx,
    int* __restrict__ offs, int NB, int N)
{
    if (threadIdx.x == 0) {
        int run = 0;
        for (int i = 0; i < NB; ++i) { partx[i] = run; run += part[i]; }
        offs[N] = run;
    }
}

__global__ __launch_bounds__(256) void scanC_kernel(
    const int* __restrict__ cnt, const int* __restrict__ partx,
    int* __restrict__ offs, int N)
{
    __shared__ int sb[256];
    const int tid  = threadIdx.x;
    const int base = blockIdx.x * 2048 + tid * 8;
    int v[8];
    int tsum = 0;
#pragma unroll
    for (int q = 0; q < 8; ++q) {
        const int i = base + q;
        v[q] = (i < N) ? cnt[i] : 0;
        tsum += v[q];
    }
    sb[tid] = tsum;
    __syncthreads();
    for (int d = 1; d < 256; d <<= 1) {
        const int t = (tid >= d) ? sb[tid - d] : 0;
        __syncthreads();
        sb[tid] += t;
        __syncthreads();
    }
    int run = partx[blockIdx.x] + sb[tid] - tsum;
#pragma unroll
    for (int q = 0; q < 8; ++q) {
        const int i = base + q;
        if (i < N) offs[i] = run;
        run += v[q];
    }
}

// ---------------------------------------------------------------------------
// scatter (blocks [0,SB)) + ntile builder (blocks [SB, SB+TB))
// ---------------------------------------------------------------------------
__global__ __launch_bounds__(256) void scatter_ntile_kernel(
    const int* __restrict__ ei, const int* __restrict__ offs,
    const int* __restrict__ rank, int4* __restrict__ re4,
    int2* __restrict__ ntile, int E, int N, int NT, int SB)
{
    const int tid = threadIdx.x;
    if ((int)blockIdx.x < SB) {
        const int e = blockIdx.x * 256 + tid;
        if (e >= E) return;
        const int row = ei[e];
        const int col = ei[E + e];
        const int pos = offs[col] + rank[e];
        re4[pos] = make_int4(row, col, e, 0);
    } else {
        const int t = ((int)blockIdx.x - SB) * 256 + tid;
        if (t >= NT) return;
        const int a = node_of(offs, N, t * 64);
        const int b = node_of(offs, N, min(t * 64 + 63, E - 1));
        ntile[t] = make_int2(a, b);
    }
}

// ---------------------------------------------------------------------------
// Barrier-free MFMA fused edge kernel: 1 wave = 64 sorted edges (unchanged).
// ---------------------------------------------------------------------------
__global__ __launch_bounds__(128) void fused_edge_mfma(
    const float* __restrict__ ea,
    const uint32_t* __restrict__ PW1, const uint32_t* __restrict__ PW2,
    const float* __restrict__ b2,
    const float* __restrict__ Pa, const float* __restrict__ Pb,
    const int4* __restrict__ re4, const int* __restrict__ offs,
    const int2* __restrict__ ntile,
    float* __restrict__ agg_sum, int* __restrict__ agg_maxb,
    int N, int E, int NT)
{
    __shared__ uint32_t smem_all[2 * 64 * 34];
    const int w    = threadIdx.x >> 6;
    const int t    = blockIdx.x * 2 + w;
    if (t >= NT) return;
    uint32_t* smem = smem_all + w * (64 * 34);
    const int lane = threadIdx.x & 63;
    const int l15  = lane & 15;
    const int l4   = lane >> 4;
    const int e0   = t * 64;
    const int e1   = min(e0 + 64, E);
    const int2 nrange = ntile[t];

    const int p = e0 + lane;
    const int4 rce = re4[min(p, E - 1)];
    {
        const float2* pa = reinterpret_cast<const float2*>(Pa + (size_t)rce.x * HIDN);
        const float2* pb = reinterpret_cast<const float2*>(Pb + (size_t)rce.y * HIDN);
        float2* dst = reinterpret_cast<float2*>(&smem[lane * 34]);
#pragma unroll
        for (int q = 0; q < 16; ++q) {
            const float2 a = pa[q], b = pb[q];
            dst[q] = make_float2(a.x + b.x, a.y + b.y);
        }
    }

    Frag B1[2][2];
#pragma unroll
    for (int nt = 0; nt < 2; ++nt)
#pragma unroll
        for (int ks = 0; ks < 2; ++ks) {
            const uint4 q = *reinterpret_cast<const uint4*>(
                &PW1[(nt * 16 + l15) * 32 + ks * 16 + l4 * 4]);
            B1[nt][ks].u[0] = q.x; B1[nt][ks].u[1] = q.y;
            B1[nt][ks].u[2] = q.z; B1[nt][ks].u[3] = q.w;
        }
    Frag B2f[4];
#pragma unroll
    for (int nt = 0; nt < 4; ++nt) {
        const uint4 q = *reinterpret_cast<const uint4*>(
            &PW2[(nt * 16 + l15) * 16 + l4 * 4]);
        B2f[nt].u[0] = q.x; B2f[nt].u[1] = q.y;
        B2f[nt].u[2] = q.z; B2f[nt].u[3] = q.w;
    }

    Frag A1[4][2];
#pragma unroll
    for (int mt = 0; mt < 4; ++mt) {
        const int eix = __shfl(rce.z, mt * 16 + l15, 64);
        const float* rp = ea + (size_t)eix * FN;
#pragma unroll
        for (int ks = 0; ks < 2; ++ks) {
            const float4* gp = reinterpret_cast<const float4*>(rp + ks * 32 + l4 * 8);
            const float4 f0 = gp[0], f1 = gp[1];
            A1[mt][ks].u[0] = packrn(f0.x, f0.y);
            A1[mt][ks].u[1] = packrn(f0.z, f0.w);
            A1[mt][ks].u[2] = packrn(f1.x, f1.y);
            A1[mt][ks].u[3] = packrn(f1.z, f1.w);
        }
    }

    f32x4 acc1[4][2];
    const float* Pl = reinterpret_cast<const float*>(smem);
#pragma unroll
    for (int mt = 0; mt < 4; ++mt)
#pragma unroll
        for (int nt = 0; nt < 2; ++nt)
#pragma unroll
            for (int r = 0; r < 4; ++r) {
                const int et = mt * 16 + l4 * 4 + r;
                acc1[mt][nt][r] = Pl[et * 34 + nt * 16 + l15];
            }
#pragma unroll
    for (int mt = 0; mt < 4; ++mt)
#pragma unroll
        for (int nt = 0; nt < 2; ++nt)
#pragma unroll
            for (int ks = 0; ks < 2; ++ks)
                acc1[mt][nt] = __builtin_amdgcn_mfma_f32_16x16x32_bf16(
                    A1[mt][ks].v, B1[nt][ks].v, acc1[mt][nt], 0, 0, 0);

    float* Hl = reinterpret_cast<float*>(smem);
#pragma unroll
    for (int mt = 0; mt < 4; ++mt)
#pragma unroll
        for (int nt = 0; nt < 2; ++nt)
#pragma unroll
            for (int r = 0; r < 4; ++r) {
                const int et = mt * 16 + l4 * 4 + r;
                Hl[et * 34 + nt * 16 + l15] = fmaxf(acc1[mt][nt][r], 0.0f);
            }

    Frag A2[4];
#pragma unroll
    for (int mt = 0; mt < 4; ++mt) {
        const float* hb = &Hl[(mt * 16 + l15) * 34 + l4 * 8];
        const float2 g0 = *reinterpret_cast<const float2*>(hb + 0);
        const float2 g1 = *reinterpret_cast<const float2*>(hb + 2);
        const float2 g2 = *reinterpret_cast<const float2*>(hb + 4);
        const float2 g3 = *reinterpret_cast<const float2*>(hb + 6);
        A2[mt].u[0] = packrn(g0.x, g0.y);
        A2[mt].u[1] = packrn(g1.x, g1.y);
        A2[mt].u[2] = packrn(g2.x, g2.y);
        A2[mt].u[3] = packrn(g3.x, g3.y);
    }

#pragma unroll
    for (int nt = 0; nt < 4; ++nt) {
        const float b2v = b2[nt * 16 + l15];
        f32x4 a2c[4];
#pragma unroll
        for (int mt = 0; mt < 4; ++mt) {
            a2c[mt] = (f32x4){0.f, 0.f, 0.f, 0.f};
            a2c[mt] = __builtin_amdgcn_mfma_f32_16x16x32_bf16(
                A2[mt].v, B2f[nt].v, a2c[mt], 0, 0, 0);
        }
        const int j = nt * 16 + l15;
#pragma unroll
        for (int mt = 0; mt < 4; ++mt)
#pragma unroll
            for (int rp2 = 0; rp2 < 2; ++rp2) {
                const int q2 = mt * 8 + l4 * 2 + rp2;
                const float v0 = fmaxf(a2c[mt][rp2 * 2]     + b2v, 0.0f);
                const float v1 = fmaxf(a2c[mt][rp2 * 2 + 1] + b2v, 0.0f);
                smem[q2 * 64 + (j ^ (((q2 >> 1) & 1) << 4))] = packrn(v0, v1);
            }
    }

    const int n0 = nrange.x, n1 = nrange.y;
    for (int n = n0; n <= n1; ++n) {
        const int s0 = offs[n], t0 = offs[n + 1];
        const int sl = max(s0, e0) - e0, tl = min(t0, e1) - e0;
        float sum = 0.0f, mx = 0.0f;
        int q = sl;
        if (q < tl && (q & 1)) {
            const int q2 = q >> 1;
            const uint32_t wv = smem[q2 * 64 + (lane ^ (((q2 >> 1) & 1) << 4))];
            const float v = bf16_to_f(wv >> 16);
            sum += v; mx = fmaxf(mx, v); ++q;
        }
        for (; q + 1 < tl; q += 2) {
            const int q2 = q >> 1;
            const uint32_t wv = smem[q2 * 64 + (lane ^ (((q2 >> 1) & 1) << 4))];
            const float v0 = bf16_to_f(wv & 0xffffu), v1 = bf16_to_f(wv >> 16);
            sum += v0 + v1; mx = fmaxf(mx, fmaxf(v0, v1));
        }
        if (q < tl) {
            const int q2 = q >> 1;
            const uint32_t wv = smem[q2 * 64 + (lane ^ (((q2 >> 1) & 1) << 4))];
            const float v = bf16_to_f(wv & 0xffffu);
            sum += v; mx = fmaxf(mx, v);
        }
        float* sp = agg_sum  + (size_t)n * FMSG + lane;
        int*   mp = agg_maxb + (size_t)n * FMSG + lane;
        if (s0 >= e0 && t0 <= e1) {
            *sp = sum;
            *mp = __float_as_int(mx);
        } else {
            unsafeAtomicAdd(sp, sum);
            atomicMax(mp, __float_as_int(mx));
        }
    }
}

// ---------------------------------------------------------------------------
// Barrier-free MFMA node kernel: 1 wave = 32 nodes, 4 waves/block (unchanged).
// ---------------------------------------------------------------------------
__global__ __launch_bounds__(256) void node_mfma(
    const float* __restrict__ Qc, const float* __restrict__ Qu,
    const int*   __restrict__ batch,
    const uint32_t* __restrict__ PW3, const uint32_t* __restrict__ PW4,
    const float* __restrict__ b4,
    const float* __restrict__ agg_sum, const int* __restrict__ agg_maxb,
    const int*   __restrict__ offs,
    float* __restrict__ out, int N)
{
    __shared__ float Hl_all[4 * 32 * 34];
    const int w    = threadIdx.x >> 6;
    float* Hl      = Hl_all + w * (32 * 34);
    const int lane = threadIdx.x & 63;
    const int l15  = lane & 15;
    const int l4   = lane >> 4;
    const int n0   = blockIdx.x * 128 + w * 32;
    if (n0 >= N) return;

    f32x4 acc1[2][2];
#pragma unroll
    for (int mt = 0; mt < 2; ++mt)
#pragma unroll
        for (int r = 0; r < 4; ++r) {
            const int nc = min(n0 + mt * 16 + l4 * 4 + r, N - 1);
            const int g  = batch[nc];
#pragma unroll
            for (int nt = 0; nt < 2; ++nt)
                acc1[mt][nt][r] = Qc[(size_t)nc * HIDN + nt * 16 + l15]
                                + Qu[(size_t)g  * HIDN + nt * 16 + l15];
        }

    int   arn[2];
    float ainv[2];
#pragma unroll
    for (int mt = 0; mt < 2; ++mt) {
        arn[mt] = min(n0 + mt * 16 + l15, N - 1);
        const int deg = offs[arn[mt] + 1] - offs[arn[mt]];
        ainv[mt] = (deg > 0) ? 1.0f / (float)deg : 0.0f;
    }

    Frag B3[2][4];
#pragma unroll
    for (int nt = 0; nt < 2; ++nt)
#pragma unroll
        for (int ks = 0; ks < 4; ++ks) {
            const uint4 q = *reinterpret_cast<const uint4*>(
                &PW3[(nt * 16 + l15) * 64 + ks * 16 + l4 * 4]);
            B3[nt][ks].u[0] = q.x; B3[nt][ks].u[1] = q.y;
            B3[nt][ks].u[2] = q.z; B3[nt][ks].u[3] = q.w;
        }

#pragma unroll
    for (int ks = 0; ks < 4; ++ks) {
        Frag A[2];
        if (ks < 2) {
#pragma unroll
            for (int mt = 0; mt < 2; ++mt) {
                const float4* gp = reinterpret_cast<const float4*>(
                    agg_sum + (size_t)arn[mt] * FMSG + ks * 32 + l4 * 8);
                const float4 f0 = gp[0], f1 = gp[1];
                const float s = ainv[mt];
                A[mt].u[0] = packrn(f0.x * s, f0.y * s);
                A[mt].u[1] = packrn(f0.z * s, f0.w * s);
                A[mt].u[2] = packrn(f1.x * s, f1.y * s);
                A[mt].u[3] = packrn(f1.z * s, f1.w * s);
            }
        } else {
#pragma unroll
            for (int mt = 0; mt < 2; ++mt) {
                const uint4* gp = reinterpret_cast<const uint4*>(
                    agg_maxb + (size_t)arn[mt] * FMSG + (ks - 2) * 32 + l4 * 8);
                const uint4 u0 = gp[0], u1 = gp[1];
                A[mt].u[0] = packrn(__uint_as_float(u0.x), __uint_as_float(u0.y));
                A[mt].u[1] = packrn(__uint_as_float(u0.z), __uint_as_float(u0.w));
                A[mt].u[2] = packrn(__uint_as_float(u1.x), __uint_as_float(u1.y));
                A[mt].u[3] = packrn(__uint_as_float(u1.z), __uint_as_float(u1.w));
            }
        }
#pragma unroll
        for (int mt = 0; mt < 2; ++mt)
#pragma unroll
            for (int nt = 0; nt < 2; ++nt)
                acc1[mt][nt] = __builtin_amdgcn_mfma_f32_16x16x32_bf16(
                    A[mt].v, B3[nt][ks].v, acc1[mt][nt], 0, 0, 0);
    }

#pragma unroll
    for (int mt = 0; mt < 2; ++mt)
#pragma unroll
        for (int nt = 0; nt < 2; ++nt)
#pragma unroll
            for (int r = 0; r < 4; ++r) {
                const int rw = mt * 16 + l4 * 4 + r;
                Hl[rw * 34 + nt * 16 + l15] = fmaxf(acc1[mt][nt][r], 0.0f);
            }

    Frag A2[2];
#pragma unroll
    for (int mt = 0; mt < 2; ++mt) {
        const float* hb = &Hl[(mt * 16 + l15) * 34 + l4 * 8];
        const float2 g0 = *reinterpret_cast<const float2*>(hb + 0);
        const float2 g1 = *reinterpret_cast<const float2*>(hb + 2);
        const float2 g2 = *reinterpret_cast<const float2*>(hb + 4);
        const float2 g3 = *reinterpret_cast<const float2*>(hb + 6);
        A2[mt].u[0] = packrn(g0.x, g0.y);
        A2[mt].u[1] = packrn(g1.x, g1.y);
        A2[mt].u[2] = packrn(g2.x, g2.y);
        A2[mt].u[3] = packrn(g3.x, g3.y);
    }

#pragma unroll
    for (int nt = 0; nt < 8; ++nt) {
        Frag B4f;
        const uint4 q = *reinterpret_cast<const uint4*>(
            &PW4[(nt * 16 + l15) * 16 + l4 * 4]);
        B4f.u[0] = q.x; B4f.u[1] = q.y; B4f.u[2] = q.z; B4f.u[3] = q.w;
        const float b4v = b4[nt * 16 + l15];
        f32x4 tacc[2];
#pragma unroll
        for (int mt = 0; mt < 2; ++mt) {
            tacc[mt] = (f32x4){0.f, 0.f, 0.f, 0.f};
            tacc[mt] = __builtin_amdgcn_mfma_f32_16x16x32_bf16(
                A2[mt].v, B4f.v, tacc[mt], 0, 0, 0);
        }
#pragma unroll
        for (int mt = 0; mt < 2; ++mt)
#pragma unroll
            for (int r = 0; r < 4; ++r) {
                const int node = n0 + mt * 16 + l4 * 4 + r;
                if (node < N)
                    out[(size_t)node * FOUT + nt * 16 + l15] =
                        fmaxf(tacc[mt][r] + b4v, 0.0f);
            }
    }
}

// ===========================================================================
extern "C" void kernel_launch(void* const* d_in, const int* in_sizes, int n_in,
                              void* d_out, int out_size, void* d_ws, size_t ws_size,
                              hipStream_t stream)
{
    const float* x     = (const float*)d_in[0];
    const int*   ei    = (const int*)  d_in[1];
    const float* ea    = (const float*)d_in[2];
    const float* u     = (const float*)d_in[3];
    const int*   batch = (const int*)  d_in[4];
    const float* W1    = (const float*)d_in[5];
    const float* b1    = (const float*)d_in[6];
    const float* W2    = (const float*)d_in[7];
    const float* b2    = (const float*)d_in[8];
    const float* W3    = (const float*)d_in[9];
    const float* b3    = (const float*)d_in[10];
    const float* W4    = (const float*)d_in[11];
    const float* b4    = (const float*)d_in[12];
    float* out = (float*)d_out;

    const int N = in_sizes[0] / FN;   // 50000
    const int E = in_sizes[1] / 2;    // 800000
    const int G = in_sizes[3] / FN;   // 64
    const int NT = (E + 63) / 64;     // 64-edge tiles

    char* wp = (char*)d_ws;
    auto take = [&](size_t bytes) -> void* {
        void* r = (void*)wp;
        wp += (bytes + 255) & ~(size_t)255;
        return r;
    };
    float*    agg_sum  = (float*)   take((size_t)N * FMSG * 4);
    int*      agg_maxb = (int*)     take((size_t)N * FMSG * 4);
    char*     zero_end = wp;                       // agg zero span (in prep_rest)
    int*      cnt      = (int*)     take((size_t)N * 4);
    int*      offs     = (int*)     take(((size_t)N + 1) * 4);
    int*      rank     = (int*)     take((size_t)E * 4);
    int4*     re4      = (int4*)    take((size_t)E * 16);
    int2*     ntile    = (int2*)    take((size_t)NT * 8);
    float*    Pa       = (float*)   take((size_t)N * HIDN * 4);
    float*    Pb       = (float*)   take((size_t)N * HIDN * 4);
    float*    Qc       = (float*)   take((size_t)N * HIDN * 4);
    float*    Qu       = (float*)   take((size_t)G * HIDN * 4);
    uint32_t* PW1      = (uint32_t*)take(1024 * 4);
    uint32_t* PW2      = (uint32_t*)take(1024 * 4);
    uint32_t* PW3      = (uint32_t*)take(2048 * 4);
    uint32_t* PW4      = (uint32_t*)take(2048 * 4);
    int*      part     = (int*)     take(64 * 4);
    int*      partx    = (int*)     take(64 * 4);

    const int BH = (E / 4 + 255) / 256;            // hist blocks
    const int BP = (N + 255) / 256;                // node_pre blocks
    const int BZ = 256;                            // agg-zero blocks
    const int NB = (N + 2047) / 2048;              // scan blocks
    const int SB = (E + 255) / 256;                // scatter blocks
    const int TB = (NT + 255) / 256;               // ntile blocks
    const size_t zquads = (size_t)(zero_end - (char*)agg_sum) / 16;

    zero_cnt_kernel<<<(N + 255) / 256, 256, 0, stream>>>(cnt, N);
    hist_kernel   <<<BH, 256, 0, stream>>>(ei, cnt, rank, E);
    prep_rest_kernel<<<BP + 1 + BZ, 256, 0, stream>>>(
        x, u, W1, b1, W2, W3, b3, W4,
        Pa, Pb, Qc, Qu, PW1, PW2, PW3, PW4,
        (uint4*)agg_sum, zquads, N, G, BP, BZ);
    scanA_kernel  <<<NB, 256, 0, stream>>>(cnt, part, N);
    scanB_kernel  <<<1, 64, 0, stream>>>(part, partx, offs, NB, N);
    scanC_kernel  <<<NB, 256, 0, stream>>>(cnt, partx, offs, N);
    scatter_ntile_kernel<<<SB + TB, 256, 0, stream>>>(
        ei, offs, rank, re4, ntile, E, N, NT, SB);
    fused_edge_mfma<<<(NT + 1) / 2, 128, 0, stream>>>(
        ea, PW1, PW2, b2, Pa, Pb, re4, offs, ntile, agg_sum, agg_maxb, N, E, NT);
    node_mfma     <<<(N + 127) / 128, 256, 0, stream>>>(
        Qc, Qu, batch, PW3, PW4, b4, agg_sum, agg_maxb, offs, out, N);
}